// Round 3
// baseline (202.850 us; speedup 1.0000x reference)
//
#include <hip/hip_runtime.h>
#include <stdint.h>

typedef int  v4i  __attribute__((ext_vector_type(4)));
typedef int  v16i __attribute__((ext_vector_type(16)));
typedef unsigned int uint32;

#define BATCH 16384
#define FEAT  1024

// ---- workspace layout (bytes) ----
// Activations in MFMA B-fragment layout: frag16B index = (nb*32 + kk)*64 + lane
//   value(byte j) = act[row = kk*32 + (j&3) + 8*(j>>2) + 4*(lane>>5)][col = nb*32 + (lane&31)]
// Weights in matching A-fragment layout (same sigma permutation of K).
// R3: W rows with BN scale < 0 are sign-folded (negated) at prep; threshold is
// a single int T2 per row, uniform test h >= T2.
#define OFF_ACTA 0u            // 16 MB  (Xp / H2)
#define OFF_ACTB 16777216u     // 16 MB  (H1 / H3)
#define OFF_WA1  33554432u     // 1 MB
#define OFF_WA2  34603008u     // 1 MB
#define OFF_WA3  35651584u     // 1 MB
#define OFF_WA4  36700160u     // 32 KB (10 rows + 22 zero-pad rows)
#define OFF_TH   36732928u     // 3*1024 int

// ---------------------------------------------------------------------------
// prep: binarize to +-1 int8 (sign-folded for W1..W3) and emit MFMA fragment
// layouts. Roles: b<512: X (thr 0.5) | 512..607: W1..W3 (fold) | 608: W4 | 609: TH
__global__ void __launch_bounds__(256) prep_kernel(
    const float* __restrict__ x,
    const float* __restrict__ W1, const float* __restrict__ W2,
    const float* __restrict__ W3, const float* __restrict__ W4,
    const float* __restrict__ g1, const float* __restrict__ b1,
    const float* __restrict__ m1, const float* __restrict__ v1,
    const float* __restrict__ g2, const float* __restrict__ b2,
    const float* __restrict__ m2, const float* __restrict__ v2,
    const float* __restrict__ g3, const float* __restrict__ b3,
    const float* __restrict__ m3, const float* __restrict__ v3,
    char* __restrict__ actA, char* __restrict__ wa1, char* __restrict__ wa2,
    char* __restrict__ wa3, char* __restrict__ wa4, int* __restrict__ TH)
{
    int b = blockIdx.x;
    if (b == 609) {                       // thresholds, sign-folded to single int
        for (int gid = threadIdx.x; gid < 3072; gid += 256) {
            int l = gid >> 10, j = gid & 1023;
            const float *g, *bb, *m, *v;
            if (l == 0)      { g = g1; bb = b1; m = m1; v = v1; }
            else if (l == 1) { g = g2; bb = b2; m = m2; v = v2; }
            else             { g = g3; bb = b3; m = m3; v = v3; }
            double gd = (double)g[j], bd = (double)bb[j], md = (double)m[j], vd = (double)v[j];
            double s = gd / sqrt(vd + 1e-5);
            int t2;
            if (s > 0.0)      t2 = (int)ceil(md - bd / s);           // bit = h >= t2
            else if (s < 0.0) t2 = -(int)floor(md - bd / s);         // folded: -h >= -ti
            else              t2 = (bd >= 0.0) ? -2000000 : 2000000; // always / never
            TH[gid] = t2;
        }
        return;
    }

    const float* src; char* dst; float thr; int nrows; int dblk;
    const float* gp = nullptr;
    if (b < 512)      { src = x  + (size_t)b * 32768;            dst = actA; dblk = b;      thr = 0.5f; nrows = 32; }
    else if (b < 544) { int mb = b - 512; src = W1 + (size_t)mb * 32768; dst = wa1; dblk = mb; thr = 0.0f; nrows = 32; gp = g1; }
    else if (b < 576) { int mb = b - 544; src = W2 + (size_t)mb * 32768; dst = wa2; dblk = mb; thr = 0.0f; nrows = 32; gp = g2; }
    else if (b < 608) { int mb = b - 576; src = W3 + (size_t)mb * 32768; dst = wa3; dblk = mb; thr = 0.0f; nrows = 32; gp = g3; }
    else              { src = W4; dst = wa4; dblk = 0; thr = 0.0f; nrows = 10; }

    __shared__ unsigned char T[32][1040];
#pragma unroll
    for (int u = 0; u < 8; ++u) {
        int unit = threadIdx.x + u * 256;      // 0..2047
        int row  = unit >> 6;                  // 0..31
        int c16  = (unit & 63) << 4;           // col base (16 floats)
        uint32 wb0 = 0, wb1 = 0, wb2 = 0, wb3 = 0;
        if (row < nrows) {
            bool flipb = gp && (gp[dblk * 32 + row] < 0.0f);
            const float* p = src + (size_t)row * 1024 + c16;
            float4 f0 = *(const float4*)(p + 0);
            float4 f1 = *(const float4*)(p + 4);
            float4 f2 = *(const float4*)(p + 8);
            float4 f3 = *(const float4*)(p + 12);
#define BY(f) ((((f) >= thr) != flipb) ? 0x01u : 0xFFu)
            wb0 = BY(f0.x) | (BY(f0.y)<<8) | (BY(f0.z)<<16) | (BY(f0.w)<<24);
            wb1 = BY(f1.x) | (BY(f1.y)<<8) | (BY(f1.z)<<16) | (BY(f1.w)<<24);
            wb2 = BY(f2.x) | (BY(f2.y)<<8) | (BY(f2.z)<<16) | (BY(f2.w)<<24);
            wb3 = BY(f3.x) | (BY(f3.y)<<8) | (BY(f3.z)<<16) | (BY(f3.w)<<24);
#undef BY
        }
        *(uint4*)&T[row][c16] = make_uint4(wb0, wb1, wb2, wb3);
    }
    __syncthreads();

    int lane = threadIdx.x & 63;
    int wv   = threadIdx.x >> 6;
    int row  = lane & 31;
    int hb   = (lane >> 5) * 4;                 // +4h byte offset of sigma
#pragma unroll
    for (int u = 0; u < 8; ++u) {
        int kk = wv * 8 + u;
        const unsigned char* tr = &T[row][kk * 32 + hb];
        uint32 w0 = *(const uint32*)(tr + 0);
        uint32 w1 = *(const uint32*)(tr + 8);
        uint32 w2 = *(const uint32*)(tr + 16);
        uint32 w3 = *(const uint32*)(tr + 24);
        *(uint4*)(dst + (((size_t)dblk * 32 + kk) * 64 + lane) * 16) = make_uint4(w0, w1, w2, w3);
    }
}

// ---------------------------------------------------------------------------
// Async stage of one 32 KB B-tile into LDS (linear copy in fragment layout).
__device__ __forceinline__ void stage_tile(v4i (*Bs)[2048], int bufi,
                                           const v4i* __restrict__ Bin,
                                           int tile, int wv, int lane) {
#pragma unroll
    for (int j = 0; j < 8; ++j) {
        __builtin_amdgcn_global_load_lds(
            (const __attribute__((address_space(1))) void*)
                (Bin + (size_t)tile * 2048 + j * 256 + wv * 64 + lane),
            (__attribute__((address_space(3))) void*)
                (&Bs[bufi][j * 256 + wv * 64]),
            16, 0, 0);
    }
}

// ---------------------------------------------------------------------------
// Binary GEMM layer on matrix cores: H^T = sign( W_folded @ Hprev^T - T2 ).
// R3: thresholds folded into acc init (LDS stash, broadcast reads); epilogue is
// a pure sign test; dual split-K acc chains; explicit 1-ahead b-frag prefetch.
// Target VGPR ~200 (scheduler headroom was the R2 bottleneck theory).
__global__ void __launch_bounds__(256, 2) gemm_i8_kernel(
    const v4i* __restrict__ Af, const v4i* __restrict__ Bin,
    const int* __restrict__ th, v4i* __restrict__ Bout)
{
    __shared__ v4i Bs[2][2048];                // 2 x 32 KB
    __shared__ int Tsh[128];
    const int tid  = threadIdx.x;
    const int lane = tid & 63;
    const int wv   = tid >> 6;
    int bid = blockIdx.x;
    int xcd = bid & 7;
    int i   = bid >> 3;
    int s   = xcd + ((i >> 3) << 3);           // n-split 0..63, XCD-grouped
    int m   = i & 7;                           // m-block (128 rows)
    int mt  = m * 4 + wv;                      // 32-row W tile 0..31
    int nb0 = s * 8;

    stage_tile(Bs, 0, Bin, nb0, wv, lane);     // tile 0 in flight
    if (tid < 128) Tsh[tid] = th[m * 128 + tid];

    // A-fragments, full K (32 x 16B = 128 VGPR)
    v4i a[32];
    {
        const v4i* Ap = Af + (size_t)mt * 2048;
#pragma unroll
        for (int kk = 0; kk < 32; ++kk) a[kk] = Ap[kk * 64 + lane];
    }
    asm volatile("s_waitcnt vmcnt(0) lgkmcnt(0)" ::: "memory");
    __builtin_amdgcn_s_barrier();

    const int hi4 = (lane >> 5) * 4;
    int buf = 0;
#pragma unroll 1
    for (int it = 0; it < 8; ++it) {
        if (it < 7) stage_tile(Bs, buf ^ 1, Bin, nb0 + it + 1, wv, lane);

        v16i acc0, acc1;
#pragma unroll
        for (int q = 0; q < 16; ++q) {
            acc0[q] = -Tsh[wv * 32 + (q & 3) + 8 * (q >> 2) + hi4];
            acc1[q] = 0;
        }

        v4i b0 = Bs[buf][lane];
        v4i b1 = Bs[buf][16 * 64 + lane];
#pragma unroll
        for (int kk = 0; kk < 16; ++kk) {
            v4i nb0f, nb1f;
            if (kk < 15) {
                nb0f = Bs[buf][(kk + 1) * 64 + lane];
                nb1f = Bs[buf][(kk + 17) * 64 + lane];
            }
            acc0 = __builtin_amdgcn_mfma_i32_32x32x32_i8(a[kk],      b0, acc0, 0, 0, 0);
            acc1 = __builtin_amdgcn_mfma_i32_32x32x32_i8(a[kk + 16], b1, acc1, 0, 0, 0);
            b0 = nb0f; b1 = nb1f;
        }

        // h = acc0+acc1 already includes -T2; byte = sign(h): +1 -> 0x01, -1 -> 0xFF
        uint32 wds0 = 0, wds1 = 0, wds2 = 0, wds3 = 0;
#pragma unroll
        for (int bq = 0; bq < 4; ++bq) {
            { int h = acc0[bq]      + acc1[bq];      wds0 |= (((uint32)((h >> 31) | 1)) & 0xFFu) << (8 * bq); }
            { int h = acc0[4 + bq]  + acc1[4 + bq];  wds1 |= (((uint32)((h >> 31) | 1)) & 0xFFu) << (8 * bq); }
            { int h = acc0[8 + bq]  + acc1[8 + bq];  wds2 |= (((uint32)((h >> 31) | 1)) & 0xFFu) << (8 * bq); }
            { int h = acc0[12 + bq] + acc1[12 + bq]; wds3 |= (((uint32)((h >> 31) | 1)) & 0xFFu) << (8 * bq); }
        }
        v4i ov; ov[0] = (int)wds0; ov[1] = (int)wds1; ov[2] = (int)wds2; ov[3] = (int)wds3;
        Bout[((size_t)(nb0 + it) * 32 + mt) * 64 + lane] = ov;

        if (it < 7) {
            // stage loads (8 per wave) must land; the output store may float.
            asm volatile("s_waitcnt vmcnt(1)" ::: "memory");
            __builtin_amdgcn_s_barrier();
            buf ^= 1;
        }
    }
}

// ---------------------------------------------------------------------------
// Final 1024 -> 10 via MFMA (W4 zero-padded to 32 rows) + TensorNorm.
// R3: spread over 256 blocks x 2 waves for better HBM pull.
__global__ void __launch_bounds__(128) final_kernel(
    const v4i* __restrict__ Af4, const v4i* __restrict__ B3,
    const float* __restrict__ tw, const float* __restrict__ tb,
    const float* __restrict__ tm, const float* __restrict__ tv,
    float* __restrict__ out)
{
    int lane = threadIdx.x & 63;
    int nb   = blockIdx.x * 2 + (threadIdx.x >> 6);
    const v4i* Bf = B3 + (size_t)nb * 2048;
    v16i acc;
#pragma unroll
    for (int z = 0; z < 16; ++z) acc[z] = 0;
#pragma unroll
    for (int kk = 0; kk < 32; ++kk) {
        v4i av = Af4[kk * 64 + lane];
        v4i bv = Bf[kk * 64 + lane];
        acc = __builtin_amdgcn_mfma_i32_32x32x32_i8(av, bv, acc, 0, 0, 0);
    }
    double sc  = (double)tw[0] / sqrt((double)tv[0] + 1e-4);
    double off = (double)tb[0] - (double)tm[0] * sc;
    int colg = nb * 32 + (lane & 31);
    int hi   = lane >> 5;
#pragma unroll
    for (int q = 0; q < 8; ++q) {
        int rr = (q & 3) + 8 * (q >> 2) + 4 * hi;
        if (rr < 10)
            out[(size_t)colg * 10 + rr] = (float)((double)acc[q] * sc + off);
    }
}

// ---------------------------------------------------------------------------
extern "C" void kernel_launch(void* const* d_in, const int* in_sizes, int n_in,
                              void* d_out, int out_size, void* d_ws, size_t ws_size,
                              hipStream_t stream) {
    const float* x  = (const float*)d_in[0];
    const float* W1 = (const float*)d_in[1];
    const float* W2 = (const float*)d_in[2];
    const float* W3 = (const float*)d_in[3];
    const float* W4 = (const float*)d_in[4];
    const float* g1 = (const float*)d_in[5];
    const float* b1 = (const float*)d_in[6];
    const float* m1 = (const float*)d_in[7];
    const float* v1 = (const float*)d_in[8];
    const float* g2 = (const float*)d_in[9];
    const float* b2 = (const float*)d_in[10];
    const float* m2 = (const float*)d_in[11];
    const float* v2 = (const float*)d_in[12];
    const float* g3 = (const float*)d_in[13];
    const float* b3 = (const float*)d_in[14];
    const float* m3 = (const float*)d_in[15];
    const float* v3 = (const float*)d_in[16];
    const float* tw = (const float*)d_in[17];
    const float* tb = (const float*)d_in[18];
    const float* tm = (const float*)d_in[19];
    const float* tv = (const float*)d_in[20];

    char* ws = (char*)d_ws;
    char* actA = ws + OFF_ACTA;
    char* actB = ws + OFF_ACTB;
    char* wa1  = ws + OFF_WA1;
    char* wa2  = ws + OFF_WA2;
    char* wa3  = ws + OFF_WA3;
    char* wa4  = ws + OFF_WA4;
    int*  TH   = (int*)(ws + OFF_TH);

    prep_kernel<<<610, 256, 0, stream>>>(x, W1, W2, W3, W4,
                                         g1, b1, m1, v1, g2, b2, m2, v2,
                                         g3, b3, m3, v3,
                                         actA, wa1, wa2, wa3, wa4, TH);

    gemm_i8_kernel<<<512, 256, 0, stream>>>((const v4i*)wa1, (const v4i*)actA, TH,        (v4i*)actB);
    gemm_i8_kernel<<<512, 256, 0, stream>>>((const v4i*)wa2, (const v4i*)actB, TH + 1024, (v4i*)actA);
    gemm_i8_kernel<<<512, 256, 0, stream>>>((const v4i*)wa3, (const v4i*)actA, TH + 2048, (v4i*)actB);

    final_kernel<<<256, 128, 0, stream>>>((const v4i*)wa4, (const v4i*)actB,
                                          tw, tb, tm, tv, (float*)d_out);
}

// Round 4
// 200.809 us; speedup vs baseline: 1.0102x; 1.0102x over previous
//
#include <hip/hip_runtime.h>
#include <stdint.h>

typedef int  v4i  __attribute__((ext_vector_type(4)));
typedef int  v16i __attribute__((ext_vector_type(16)));
typedef unsigned int uint32;

#define BATCH 16384
#define FEAT  1024

// ---- workspace layout (bytes) ----
// Activations in MFMA B-fragment layout: frag16B index = (nb*32 + kk)*64 + lane
//   value(byte j) = act[row = kk*32 + (j&3) + 8*(j>>2) + 4*(lane>>5)][col = nb*32 + (lane&31)]
// Weights in matching A-fragment layout (same sigma permutation of K).
// W rows with BN scale < 0 are sign-folded (negated) at prep; threshold is a
// single int T2 per row, uniform test h >= T2.
#define OFF_ACTA 0u            // 16 MB  (Xp / H2)
#define OFF_ACTB 16777216u     // 16 MB  (H1 / H3)
#define OFF_WA1  33554432u     // 1 MB
#define OFF_WA2  34603008u     // 1 MB
#define OFF_WA3  35651584u     // 1 MB
#define OFF_WA4  36700160u     // 32 KB (10 rows + 22 zero-pad rows)
#define OFF_TH   36732928u     // 3*1024 int

// ---------------------------------------------------------------------------
// prep: binarize to +-1 int8 (sign-folded for W1..W3) and emit MFMA fragment
// layouts. Roles: b<512: X (thr 0.5) | 512..607: W1..W3 (fold) | 608: W4 | 609: TH
__global__ void __launch_bounds__(256) prep_kernel(
    const float* __restrict__ x,
    const float* __restrict__ W1, const float* __restrict__ W2,
    const float* __restrict__ W3, const float* __restrict__ W4,
    const float* __restrict__ g1, const float* __restrict__ b1,
    const float* __restrict__ m1, const float* __restrict__ v1,
    const float* __restrict__ g2, const float* __restrict__ b2,
    const float* __restrict__ m2, const float* __restrict__ v2,
    const float* __restrict__ g3, const float* __restrict__ b3,
    const float* __restrict__ m3, const float* __restrict__ v3,
    char* __restrict__ actA, char* __restrict__ wa1, char* __restrict__ wa2,
    char* __restrict__ wa3, char* __restrict__ wa4, int* __restrict__ TH)
{
    int b = blockIdx.x;
    if (b == 609) {                       // thresholds, sign-folded to single int
        for (int gid = threadIdx.x; gid < 3072; gid += 256) {
            int l = gid >> 10, j = gid & 1023;
            const float *g, *bb, *m, *v;
            if (l == 0)      { g = g1; bb = b1; m = m1; v = v1; }
            else if (l == 1) { g = g2; bb = b2; m = m2; v = v2; }
            else             { g = g3; bb = b3; m = m3; v = v3; }
            double gd = (double)g[j], bd = (double)bb[j], md = (double)m[j], vd = (double)v[j];
            double s = gd / sqrt(vd + 1e-5);
            int t2;
            if (s > 0.0)      t2 = (int)ceil(md - bd / s);           // bit = h >= t2
            else if (s < 0.0) t2 = -(int)floor(md - bd / s);         // folded: -h >= -ti
            else              t2 = (bd >= 0.0) ? -2000000 : 2000000; // always / never
            TH[gid] = t2;
        }
        return;
    }

    const float* src; char* dst; float thr; int nrows; int dblk;
    const float* gp = nullptr;
    if (b < 512)      { src = x  + (size_t)b * 32768;            dst = actA; dblk = b;      thr = 0.5f; nrows = 32; }
    else if (b < 544) { int mb = b - 512; src = W1 + (size_t)mb * 32768; dst = wa1; dblk = mb; thr = 0.0f; nrows = 32; gp = g1; }
    else if (b < 576) { int mb = b - 544; src = W2 + (size_t)mb * 32768; dst = wa2; dblk = mb; thr = 0.0f; nrows = 32; gp = g2; }
    else if (b < 608) { int mb = b - 576; src = W3 + (size_t)mb * 32768; dst = wa3; dblk = mb; thr = 0.0f; nrows = 32; gp = g3; }
    else              { src = W4; dst = wa4; dblk = 0; thr = 0.0f; nrows = 10; }

    __shared__ unsigned char T[32][1040];
#pragma unroll
    for (int u = 0; u < 8; ++u) {
        int unit = threadIdx.x + u * 256;      // 0..2047
        int row  = unit >> 6;                  // 0..31
        int c16  = (unit & 63) << 4;           // col base (16 floats)
        uint32 wb0 = 0, wb1 = 0, wb2 = 0, wb3 = 0;
        if (row < nrows) {
            bool flipb = gp && (gp[dblk * 32 + row] < 0.0f);
            const float* p = src + (size_t)row * 1024 + c16;
            float4 f0 = *(const float4*)(p + 0);
            float4 f1 = *(const float4*)(p + 4);
            float4 f2 = *(const float4*)(p + 8);
            float4 f3 = *(const float4*)(p + 12);
#define BY(f) ((((f) >= thr) != flipb) ? 0x01u : 0xFFu)
            wb0 = BY(f0.x) | (BY(f0.y)<<8) | (BY(f0.z)<<16) | (BY(f0.w)<<24);
            wb1 = BY(f1.x) | (BY(f1.y)<<8) | (BY(f1.z)<<16) | (BY(f1.w)<<24);
            wb2 = BY(f2.x) | (BY(f2.y)<<8) | (BY(f2.z)<<16) | (BY(f2.w)<<24);
            wb3 = BY(f3.x) | (BY(f3.y)<<8) | (BY(f3.z)<<16) | (BY(f3.w)<<24);
#undef BY
        }
        *(uint4*)&T[row][c16] = make_uint4(wb0, wb1, wb2, wb3);
    }
    __syncthreads();

    int lane = threadIdx.x & 63;
    int wv   = threadIdx.x >> 6;
    int row  = lane & 31;
    int hb   = (lane >> 5) * 4;                 // +4h byte offset of sigma
#pragma unroll
    for (int u = 0; u < 8; ++u) {
        int kk = wv * 8 + u;
        const unsigned char* tr = &T[row][kk * 32 + hb];
        uint32 w0 = *(const uint32*)(tr + 0);
        uint32 w1 = *(const uint32*)(tr + 8);
        uint32 w2 = *(const uint32*)(tr + 16);
        uint32 w3 = *(const uint32*)(tr + 24);
        *(uint4*)(dst + (((size_t)dblk * 32 + kk) * 64 + lane) * 16) = make_uint4(w0, w1, w2, w3);
    }
}

// ---------------------------------------------------------------------------
__device__ __forceinline__ void gload16(const v4i* gsrc, v4i* ldst) {
    __builtin_amdgcn_global_load_lds(
        (const __attribute__((address_space(1))) void*)gsrc,
        (__attribute__((address_space(3))) void*)ldst, 16, 0, 0);
}

// ---------------------------------------------------------------------------
// Binary GEMM layer on matrix cores: H^T = sign( W_folded @ Hprev^T - T2 ).
// R4: 8-phase inner schedule (T3/T5): per phase, batch-issue 4 ds_read_b128 for
// phase p+1, then setprio(1) + 4 MFMAs + setprio(0). Steady-state LDS latency
// fully covered (R2/R3's 1-ahead pair left ~60cyc exposed per 2 MFMAs).
// Stage loads for next tile spread 2/phase over phases 0..3. Thresholds hoisted
// to regs once. Counted vmcnt(1) + raw barrier per tile.
__global__ void __launch_bounds__(256, 2) gemm_i8_kernel(
    const v4i* __restrict__ Af, const v4i* __restrict__ Bin,
    const int* __restrict__ th, v4i* __restrict__ Bout)
{
    __shared__ v4i Bs[2][2048];                // 2 x 32 KB
    __shared__ int Tsh[128];
    const int tid  = threadIdx.x;
    const int lane = tid & 63;
    const int wv   = tid >> 6;
    int bid = blockIdx.x;
    int xcd = bid & 7;
    int i   = bid >> 3;
    int s   = xcd + ((i >> 3) << 3);           // n-split 0..63, XCD-grouped
    int m   = i & 7;                           // m-block (128 rows)
    int mt  = m * 4 + wv;                      // 32-row W tile 0..31
    int nb0 = s * 8;

    // stage tile 0 (8 gload_lds per wave)
#pragma unroll
    for (int j = 0; j < 8; ++j)
        gload16(Bin + (size_t)nb0 * 2048 + j * 256 + wv * 64 + lane,
                &Bs[0][j * 256 + wv * 64]);
    if (tid < 128) Tsh[tid] = th[m * 128 + tid];

    // A-fragments, full K (32 x 16B = 128 VGPR)
    v4i a[32];
    {
        const v4i* Ap = Af + (size_t)mt * 2048;
#pragma unroll
        for (int kk = 0; kk < 32; ++kk) a[kk] = Ap[kk * 64 + lane];
    }
    asm volatile("s_waitcnt vmcnt(0) lgkmcnt(0)" ::: "memory");
    __builtin_amdgcn_s_barrier();

    // hoist thresholds (negated) into 16 regs, C-layout order
    const int hi4 = (lane >> 5) * 4;
    int tq[16];
#pragma unroll
    for (int q = 0; q < 16; ++q) tq[q] = -Tsh[wv * 32 + (q & 3) + 8 * (q >> 2) + hi4];

    int buf = 0;
#pragma unroll 1
    for (int it = 0; it < 8; ++it) {
        const v4i* Bb = &Bs[buf][0];
        v4i* Bn = &Bs[buf ^ 1][0];
        const v4i* gnext = Bin + (size_t)(nb0 + it + 1) * 2048;

        v16i acc0, acc1;
#pragma unroll
        for (int q = 0; q < 16; ++q) { acc0[q] = tq[q]; acc1[q] = 0; }

        // phase-0 fragments
        v4i c0 = Bb[0 * 64 + lane], c1 = Bb[1 * 64 + lane];
        v4i c2 = Bb[16 * 64 + lane], c3 = Bb[17 * 64 + lane];

#pragma unroll
        for (int p = 0; p < 8; ++p) {
            v4i n0, n1, n2, n3;
            if (p < 7) {                       // batch-issue next phase's 4 reads
                n0 = Bb[(2 * p + 2) * 64 + lane];
                n1 = Bb[(2 * p + 3) * 64 + lane];
                n2 = Bb[(18 + 2 * p) * 64 + lane];
                n3 = Bb[(19 + 2 * p) * 64 + lane];
            }
            if (p < 4 && it < 7) {             // spread next-tile staging
                int j = 2 * p;
                gload16(gnext + j * 256 + wv * 64 + lane,       Bn + j * 256 + wv * 64);
                gload16(gnext + (j + 1) * 256 + wv * 64 + lane, Bn + (j + 1) * 256 + wv * 64);
            }
            __builtin_amdgcn_s_setprio(1);
            acc0 = __builtin_amdgcn_mfma_i32_32x32x32_i8(a[2 * p],      c0, acc0, 0, 0, 0);
            acc1 = __builtin_amdgcn_mfma_i32_32x32x32_i8(a[16 + 2 * p], c2, acc1, 0, 0, 0);
            acc0 = __builtin_amdgcn_mfma_i32_32x32x32_i8(a[2 * p + 1],  c1, acc0, 0, 0, 0);
            acc1 = __builtin_amdgcn_mfma_i32_32x32x32_i8(a[17 + 2 * p], c3, acc1, 0, 0, 0);
            __builtin_amdgcn_s_setprio(0);
            c0 = n0; c1 = n1; c2 = n2; c3 = n3;
        }

        // h = acc0+acc1 already includes -T2; byte = sign(h): +1 -> 0x01, -1 -> 0xFF
        uint32 wds0 = 0, wds1 = 0, wds2 = 0, wds3 = 0;
#pragma unroll
        for (int bq = 0; bq < 4; ++bq) {
            { int h = acc0[bq]      + acc1[bq];      wds0 |= (((uint32)((h >> 31) | 1)) & 0xFFu) << (8 * bq); }
            { int h = acc0[4 + bq]  + acc1[4 + bq];  wds1 |= (((uint32)((h >> 31) | 1)) & 0xFFu) << (8 * bq); }
            { int h = acc0[8 + bq]  + acc1[8 + bq];  wds2 |= (((uint32)((h >> 31) | 1)) & 0xFFu) << (8 * bq); }
            { int h = acc0[12 + bq] + acc1[12 + bq]; wds3 |= (((uint32)((h >> 31) | 1)) & 0xFFu) << (8 * bq); }
        }
        v4i ov; ov[0] = (int)wds0; ov[1] = (int)wds1; ov[2] = (int)wds2; ov[3] = (int)wds3;
        Bout[((size_t)(nb0 + it) * 32 + mt) * 64 + lane] = ov;

        if (it < 7) {
            // stage loads (8/wave) must land; the output store may float.
            asm volatile("s_waitcnt vmcnt(1)" ::: "memory");
            __builtin_amdgcn_s_barrier();
            buf ^= 1;
        }
    }
}

// ---------------------------------------------------------------------------
// Final 1024 -> 10 via MFMA (W4 zero-padded to 32 rows) + TensorNorm.
__global__ void __launch_bounds__(128) final_kernel(
    const v4i* __restrict__ Af4, const v4i* __restrict__ B3,
    const float* __restrict__ tw, const float* __restrict__ tb,
    const float* __restrict__ tm, const float* __restrict__ tv,
    float* __restrict__ out)
{
    int lane = threadIdx.x & 63;
    int nb   = blockIdx.x * 2 + (threadIdx.x >> 6);
    const v4i* Bf = B3 + (size_t)nb * 2048;
    v16i acc;
#pragma unroll
    for (int z = 0; z < 16; ++z) acc[z] = 0;
#pragma unroll
    for (int kk = 0; kk < 32; ++kk) {
        v4i av = Af4[kk * 64 + lane];
        v4i bv = Bf[kk * 64 + lane];
        acc = __builtin_amdgcn_mfma_i32_32x32x32_i8(av, bv, acc, 0, 0, 0);
    }
    double sc  = (double)tw[0] / sqrt((double)tv[0] + 1e-4);
    double off = (double)tb[0] - (double)tm[0] * sc;
    int colg = nb * 32 + (lane & 31);
    int hi   = lane >> 5;
#pragma unroll
    for (int q = 0; q < 8; ++q) {
        int rr = (q & 3) + 8 * (q >> 2) + 4 * hi;
        if (rr < 10)
            out[(size_t)colg * 10 + rr] = (float)((double)acc[q] * sc + off);
    }
}

// ---------------------------------------------------------------------------
extern "C" void kernel_launch(void* const* d_in, const int* in_sizes, int n_in,
                              void* d_out, int out_size, void* d_ws, size_t ws_size,
                              hipStream_t stream) {
    const float* x  = (const float*)d_in[0];
    const float* W1 = (const float*)d_in[1];
    const float* W2 = (const float*)d_in[2];
    const float* W3 = (const float*)d_in[3];
    const float* W4 = (const float*)d_in[4];
    const float* g1 = (const float*)d_in[5];
    const float* b1 = (const float*)d_in[6];
    const float* m1 = (const float*)d_in[7];
    const float* v1 = (const float*)d_in[8];
    const float* g2 = (const float*)d_in[9];
    const float* b2 = (const float*)d_in[10];
    const float* m2 = (const float*)d_in[11];
    const float* v2 = (const float*)d_in[12];
    const float* g3 = (const float*)d_in[13];
    const float* b3 = (const float*)d_in[14];
    const float* m3 = (const float*)d_in[15];
    const float* v3 = (const float*)d_in[16];
    const float* tw = (const float*)d_in[17];
    const float* tb = (const float*)d_in[18];
    const float* tm = (const float*)d_in[19];
    const float* tv = (const float*)d_in[20];

    char* ws = (char*)d_ws;
    char* actA = ws + OFF_ACTA;
    char* actB = ws + OFF_ACTB;
    char* wa1  = ws + OFF_WA1;
    char* wa2  = ws + OFF_WA2;
    char* wa3  = ws + OFF_WA3;
    char* wa4  = ws + OFF_WA4;
    int*  TH   = (int*)(ws + OFF_TH);

    prep_kernel<<<610, 256, 0, stream>>>(x, W1, W2, W3, W4,
                                         g1, b1, m1, v1, g2, b2, m2, v2,
                                         g3, b3, m3, v3,
                                         actA, wa1, wa2, wa3, wa4, TH);

    gemm_i8_kernel<<<512, 256, 0, stream>>>((const v4i*)wa1, (const v4i*)actA, TH,        (v4i*)actB);
    gemm_i8_kernel<<<512, 256, 0, stream>>>((const v4i*)wa2, (const v4i*)actB, TH + 1024, (v4i*)actA);
    gemm_i8_kernel<<<512, 256, 0, stream>>>((const v4i*)wa3, (const v4i*)actA, TH + 2048, (v4i*)actB);

    final_kernel<<<256, 128, 0, stream>>>((const v4i*)wa4, (const v4i*)actB,
                                          tw, tb, tm, tv, (float*)d_out);
}